// Round 8
// baseline (258.530 us; speedup 1.0000x reference)
//
#include <hip/hip_runtime.h>

#define NROWS 4096
#define DIM   128
#define KCLS  4
#define NTILE 64                 // 64x64 anchor tiles
#define NTRI  2080               // NTILE*(NTILE+1)/2 triangular blocks
#define MARGIN_F 0.02f
#define EPS_F    1e-12f

typedef unsigned short ushort_t;
typedef unsigned int   uint_t;
typedef __attribute__((ext_vector_type(8)))  short bf16x8;
typedef __attribute__((ext_vector_type(16))) float f32x16;

__device__ __forceinline__ ushort_t rne_bf16(float v, float& back) {
    uint_t u = __float_as_uint(v);
    uint_t r = (u + 0x7fffu + ((u >> 16) & 1u)) >> 16;
    back = __uint_as_float(r << 16);
    return (ushort_t)r;
}

__device__ __forceinline__ bf16x8 pack8(const ushort_t* h) {
    bf16x8 v;
#pragma unroll
    for (int e = 0; e < 8; ++e) v[e] = (short)h[e];
    return v;
}

// triangular decode: bid -> (ti, tj), tj >= ti
__device__ __forceinline__ void tri_decode(int bid, int& ti, int& tj) {
    const int bidp = (NTRI - 1) - bid;
    int m = (int)((sqrtf((float)(8 * bidp + 1)) - 1.0f) * 0.5f);
    while ((m + 1) * (m + 2) / 2 <= bidp) ++m;
    while (m * (m + 1) / 2 > bidp) --m;
    ti = (NTILE - 1) - m;
    tj = (NTILE - 1) - (bidp - m * (m + 1) / 2);
}

// ---------------- kernel 1: fully-parallel prep ----------------
// 16-lane groups; group g<4096: anchor g (norm + bf16 hi/lo split into
// fragment-major xf); else pos-pair (a,o): direct diff^2 distance.
// xf layout: shorts, block(band,c,plane)= (band*8+c)*2+plane, 512 shorts/blk,
// within: (khalf*32 + row&31)*8 + e  -> a wave's fragment load = 1KB contiguous.
__global__ __launch_bounds__(256) void k_prep(
    const float* __restrict__ x, float* __restrict__ sqn,
    float* __restrict__ posd, ushort_t* __restrict__ xf,
    uint_t* __restrict__ imask, uint_t* __restrict__ jmask)
{
    if (blockIdx.x == 0) {
        const int tt = threadIdx.x;
        if (tt < 128) imask[tt] = 0u; else jmask[tt - 128] = 0u;
    }
    const int g  = blockIdx.x * 16 + (threadIdx.x >> 4);
    const int ln = threadIdx.x & 15;

    if (g < NROWS) {                       // ---- anchor task ----
        const int a = g;
        const float4* row = (const float4*)(x + (size_t)a * DIM);
        const float4 v0 = row[ln * 2], v1 = row[ln * 2 + 1];
        const float vs[8] = {v0.x, v0.y, v0.z, v0.w, v1.x, v1.y, v1.z, v1.w};

        float s = 0.f;
#pragma unroll
        for (int e = 0; e < 8; ++e) s += vs[e] * vs[e];
#pragma unroll
        for (int off = 1; off < 16; off <<= 1) s += __shfl_xor(s, off, 16);
        if (ln == 0) sqn[a] = s;

        ushort_t hs[8], lo[8];
#pragma unroll
        for (int e = 0; e < 8; ++e) {
            float back, d_;
            hs[e] = rne_bf16(vs[e], back);
            lo[e] = rne_bf16(vs[e] - back, d_);
        }
        const int band = a >> 5, L = a & 31, c = ln >> 1, sf = ln & 1;
        ushort_t* dst = xf + ((size_t)(band * 8 + c) * 2) * 512
                           + ((sf << 5) + L) * 8;
        *(bf16x8*)dst         = pack8(hs);
        *(bf16x8*)(dst + 512) = pack8(lo);
    } else if (g < NROWS * 4) {            // ---- pos-pair task ----
        const int idx = g - NROWS;
        const int a = idx / 3, o = idx - a * 3;
        const int cs = a & ~(KCLS - 1), pic = a & (KCLS - 1);
        const int p = cs + o + (o >= pic ? 1 : 0);
        const float4* ra = (const float4*)(x + (size_t)a * DIM);
        const float4* rp = (const float4*)(x + (size_t)p * DIM);
        float d2 = 0.f;
#pragma unroll
        for (int q = 0; q < 2; ++q) {
            const float4 A = ra[ln * 2 + q], P = rp[ln * 2 + q];
            const float dx = A.x - P.x, dy = A.y - P.y;
            const float dz = A.z - P.z, dw = A.w - P.w;
            d2 += dx * dx + dy * dy + dz * dz + dw * dw;
        }
#pragma unroll
        for (int off = 1; off < 16; off <<= 1) d2 += __shfl_xor(d2, off, 16);
        if (ln == 0) posd[(a << 2) + o] = sqrtf(fmaxf(d2, EPS_F));
    }
}

// ---------------- kernel 2: MFMA Gram + fused hinge (coalesced frags) -------
__global__ __launch_bounds__(256, 8) void k_tiles(
    const ushort_t* __restrict__ xf,
    const float* __restrict__ sqn, const float4* __restrict__ posd4,
    uint_t* __restrict__ imask, uint_t* __restrict__ jmask,
    float4* __restrict__ partial)
{
    int ti, tj;
    tri_decode((int)blockIdx.x, ti, tj);

    const int t    = threadIdx.x;
    const int wave = t >> 6, lane = t & 63;
    const int wr = wave >> 1, wc = wave & 1;
    const int col = lane & 31, hi = lane >> 5;
    const int ibase = ti << 6, jbase = tj << 6;
    const bool diag = (ti == tj);

    const int bi = (ti << 1) + wr, bj = (tj << 1) + wc;
    const ushort_t* pa = xf + (size_t)bi * 8192 + lane * 8;
    const ushort_t* pb = xf + (size_t)bj * 8192 + lane * 8;

    f32x16 acc;
#pragma unroll
    for (int r = 0; r < 16; ++r) acc[r] = 0.f;

#pragma unroll
    for (int c = 0; c < 8; ++c) {
        const bf16x8 ah = *(const bf16x8*)(pa + c * 1024);
        const bf16x8 al = *(const bf16x8*)(pa + c * 1024 + 512);
        const bf16x8 bh = *(const bf16x8*)(pb + c * 1024);
        const bf16x8 bl = *(const bf16x8*)(pb + c * 1024 + 512);
        acc = __builtin_amdgcn_mfma_f32_32x32x16_bf16(ah, bh, acc, 0, 0, 0);
        acc = __builtin_amdgcn_mfma_f32_32x32x16_bf16(ah, bl, acc, 0, 0, 0);
        acc = __builtin_amdgcn_mfma_f32_32x32x16_bf16(al, bh, acc, 0, 0, 0);
    }

    // ---------------- epilogue (identical to round 7, verified) ------------
    const int jg = jbase + (wc << 5) + col;
    const float sqj = sqn[jg];
    const float4 pj = posd4[jg];
    const float sqi_l = sqn[ibase + (wr << 5) + col];
    const float4 pi_l = posd4[ibase + (wr << 5) + col];

    float ts = 0.f, ns = 0.f, cntf = 0.f;
    uint_t iam = 0, jany = 0;
    const int jcls = jg >> 2;
#pragma unroll
    for (int r = 0; r < 16; ++r) {
        const int rbase = (r & 3) + ((r >> 2) << 3);
        const int src = rbase + (hi << 2);
        const float sqi = __shfl(sqi_l, src);
        const float p0  = __shfl(pi_l.x, src);
        const float p1  = __shfl(pi_l.y, src);
        const float p2  = __shfl(pi_l.z, src);
        const int i = ibase + (wr << 5) + src;
        const bool skip = diag && ((i >> 2) == jcls);
        const float dd = sqrtf(fmaxf(sqi + sqj - 2.f * acc[r], EPS_F));
        if (!skip) {
            ns += dd;
            const float t0 = p0 + MARGIN_F - dd;
            const float t1 = p1 + MARGIN_F - dd;
            const float t2 = p2 + MARGIN_F - dd;
            uint_t v = 0;
            if (t0 > 0.f) { ts += t0; cntf += 1.f; v = 1u; }
            if (t1 > 0.f) { ts += t1; cntf += 1.f; v = 1u; }
            if (t2 > 0.f) { ts += t2; cntf += 1.f; v = 1u; }
            iam |= v << r;
            if (!diag) {
                ns += dd;
                const float u0 = pj.x + MARGIN_F - dd;
                const float u1 = pj.y + MARGIN_F - dd;
                const float u2 = pj.z + MARGIN_F - dd;
                if (u0 > 0.f) { ts += u0; cntf += 1.f; jany = 1u; }
                if (u1 > 0.f) { ts += u1; cntf += 1.f; jany = 1u; }
                if (u2 > 0.f) { ts += u2; cntf += 1.f; jany = 1u; }
            }
        }
    }

    uint_t iam_all = iam;
#pragma unroll
    for (int off = 1; off < 32; off <<= 1) iam_all |= __shfl_xor(iam_all, off);
    uint_t rowmask = 0;
#pragma unroll
    for (int r = 0; r < 16; ++r)
        if ((iam_all >> r) & 1u)
            rowmask |= 1u << ((r & 3) + ((r >> 2) << 3) + (hi << 2));
    if ((lane == 0 || lane == 32) && rowmask)
        atomicOr(&imask[(ti << 1) + wr], rowmask);

    const unsigned long long bm = __ballot(jany != 0);
    const uint_t jm = (uint_t)bm | (uint_t)(bm >> 32);
    if (lane == 0 && jm) atomicOr(&jmask[(tj << 1) + wc], jm);

#pragma unroll
    for (int off = 32; off; off >>= 1) {
        ts   += __shfl_down(ts, off);
        ns   += __shfl_down(ns, off);
        cntf += __shfl_down(cntf, off);
    }
    __shared__ float4 wpart[4];
    if (lane == 0) wpart[wave] = make_float4(ts, ns, cntf, 0.f);
    __syncthreads();
    if (t == 0) {
        float4 s = wpart[0];
        s.x += wpart[1].x + wpart[2].x + wpart[3].x;
        s.y += wpart[1].y + wpart[2].y + wpart[3].y;
        s.z += wpart[1].z + wpart[2].z + wpart[3].z;
        partial[blockIdx.x] = s;
    }
}

// ---------------- ABLATION kernels (diagnostic; write to scratch) ----------
__global__ __launch_bounds__(256, 8) void kt_ldm(
    const ushort_t* __restrict__ xf, float* __restrict__ scratch)
{
    int ti, tj; tri_decode((int)blockIdx.x, ti, tj);
    const int t = threadIdx.x, wave = t >> 6, lane = t & 63;
    const int wr = wave >> 1, wc = wave & 1;
    const int bi = (ti << 1) + wr, bj = (tj << 1) + wc;
    const ushort_t* pa = xf + (size_t)bi * 8192 + lane * 8;
    const ushort_t* pb = xf + (size_t)bj * 8192 + lane * 8;
    f32x16 acc;
#pragma unroll
    for (int r = 0; r < 16; ++r) acc[r] = 0.f;
#pragma unroll
    for (int c = 0; c < 8; ++c) {
        const bf16x8 ah = *(const bf16x8*)(pa + c * 1024);
        const bf16x8 al = *(const bf16x8*)(pa + c * 1024 + 512);
        const bf16x8 bh = *(const bf16x8*)(pb + c * 1024);
        const bf16x8 bl = *(const bf16x8*)(pb + c * 1024 + 512);
        acc = __builtin_amdgcn_mfma_f32_32x32x16_bf16(ah, bh, acc, 0, 0, 0);
        acc = __builtin_amdgcn_mfma_f32_32x32x16_bf16(ah, bl, acc, 0, 0, 0);
        acc = __builtin_amdgcn_mfma_f32_32x32x16_bf16(al, bh, acc, 0, 0, 0);
    }
    float s = 0.f;
#pragma unroll
    for (int r = 0; r < 16; ++r) s += acc[r];
#pragma unroll
    for (int off = 32; off; off >>= 1) s += __shfl_down(s, off);
    if (lane == 0) scratch[blockIdx.x * 4 + wave] = s;
}

__global__ __launch_bounds__(256, 8) void kt_epi(
    const float* __restrict__ sqn, const float4* __restrict__ posd4,
    uint_t* __restrict__ imask2, uint_t* __restrict__ jmask2,
    float4* __restrict__ partial2)
{
    int ti, tj; tri_decode((int)blockIdx.x, ti, tj);
    const int t = threadIdx.x, wave = t >> 6, lane = t & 63;
    const int wr = wave >> 1, wc = wave & 1;
    const int col = lane & 31, hi = lane >> 5;
    const int ibase = ti << 6, jbase = tj << 6;
    const bool diag = (ti == tj);

    f32x16 acc;                            // fake, lane/r dependent
#pragma unroll
    for (int r = 0; r < 16; ++r)
        acc[r] = (float)(((lane * 29 + r * 13) & 63)) * 0.37f - 11.f;

    const int jg = jbase + (wc << 5) + col;
    const float sqj = sqn[jg];
    const float4 pj = posd4[jg];
    const float sqi_l = sqn[ibase + (wr << 5) + col];
    const float4 pi_l = posd4[ibase + (wr << 5) + col];

    float ts = 0.f, ns = 0.f, cntf = 0.f;
    uint_t iam = 0, jany = 0;
    const int jcls = jg >> 2;
#pragma unroll
    for (int r = 0; r < 16; ++r) {
        const int rbase = (r & 3) + ((r >> 2) << 3);
        const int src = rbase + (hi << 2);
        const float sqi = __shfl(sqi_l, src);
        const float p0  = __shfl(pi_l.x, src);
        const float p1  = __shfl(pi_l.y, src);
        const float p2  = __shfl(pi_l.z, src);
        const int i = ibase + (wr << 5) + src;
        const bool skip = diag && ((i >> 2) == jcls);
        const float dd = sqrtf(fmaxf(sqi + sqj - 2.f * acc[r], EPS_F));
        if (!skip) {
            ns += dd;
            const float t0 = p0 + MARGIN_F - dd;
            const float t1 = p1 + MARGIN_F - dd;
            const float t2 = p2 + MARGIN_F - dd;
            uint_t v = 0;
            if (t0 > 0.f) { ts += t0; cntf += 1.f; v = 1u; }
            if (t1 > 0.f) { ts += t1; cntf += 1.f; v = 1u; }
            if (t2 > 0.f) { ts += t2; cntf += 1.f; v = 1u; }
            iam |= v << r;
            if (!diag) {
                ns += dd;
                const float u0 = pj.x + MARGIN_F - dd;
                const float u1 = pj.y + MARGIN_F - dd;
                const float u2 = pj.z + MARGIN_F - dd;
                if (u0 > 0.f) { ts += u0; cntf += 1.f; jany = 1u; }
                if (u1 > 0.f) { ts += u1; cntf += 1.f; jany = 1u; }
                if (u2 > 0.f) { ts += u2; cntf += 1.f; jany = 1u; }
            }
        }
    }
    uint_t iam_all = iam;
#pragma unroll
    for (int off = 1; off < 32; off <<= 1) iam_all |= __shfl_xor(iam_all, off);
    uint_t rowmask = 0;
#pragma unroll
    for (int r = 0; r < 16; ++r)
        if ((iam_all >> r) & 1u)
            rowmask |= 1u << ((r & 3) + ((r >> 2) << 3) + (hi << 2));
    if ((lane == 0 || lane == 32) && rowmask)
        atomicOr(&imask2[(ti << 1) + wr], rowmask);
    const unsigned long long bm = __ballot(jany != 0);
    const uint_t jm = (uint_t)bm | (uint_t)(bm >> 32);
    if (lane == 0 && jm) atomicOr(&jmask2[(tj << 1) + wc], jm);
#pragma unroll
    for (int off = 32; off; off >>= 1) {
        ts   += __shfl_down(ts, off);
        ns   += __shfl_down(ns, off);
        cntf += __shfl_down(cntf, off);
    }
    __shared__ float4 wpart[4];
    if (lane == 0) wpart[wave] = make_float4(ts, ns, cntf, 0.f);
    __syncthreads();
    if (t == 0) {
        float4 s = wpart[0];
        s.x += wpart[1].x + wpart[2].x + wpart[3].x;
        s.y += wpart[1].y + wpart[2].y + wpart[3].y;
        s.z += wpart[1].z + wpart[2].z + wpart[3].z;
        partial2[blockIdx.x] = s;
    }
}

__global__ __launch_bounds__(256, 8) void kt_shell(float* __restrict__ scratch)
{
    int ti, tj; tri_decode((int)blockIdx.x, ti, tj);
    if (threadIdx.x == 0) scratch[blockIdx.x] = (float)(ti + tj);
}

// ---------------- kernel 3: finalize ----------------
__global__ void k_final(const uint_t* __restrict__ imask,
                        const uint_t* __restrict__ jmask,
                        const float4* __restrict__ partial,
                        const float4* __restrict__ posd4,
                        float* __restrict__ out)
{
    const int t = threadIdx.x;      // 1024
    const int lane = t & 63, wave = t >> 6;
    double ts = 0.0, ns = 0.0, cnt = 0.0, ps = 0.0;
    uint_t zc = 0;

    for (int idx = t; idx < NTRI; idx += 1024) {
        const float4 p = partial[idx];
        ts += (double)p.x; ns += (double)p.y; cnt += (double)p.z;
    }
    for (int idx = t; idx < NROWS; idx += 1024) {
        const float4 p = posd4[idx];
        ps += (double)p.x + (double)p.y + (double)p.z;
    }
    if (t < 128) zc = 32u - (uint_t)__popc(imask[t] | jmask[t]);

#pragma unroll
    for (int off = 32; off; off >>= 1) {
        ts  += __shfl_down(ts, off);
        ns  += __shfl_down(ns, off);
        cnt += __shfl_down(cnt, off);
        ps  += __shfl_down(ps, off);
        zc  += __shfl_down(zc, off);
    }
    __shared__ double s0[16], s1[16], s2[16], s3[16];
    __shared__ uint_t s4[16];
    if (lane == 0) { s0[wave]=ts; s1[wave]=ns; s2[wave]=cnt; s3[wave]=ps; s4[wave]=zc; }
    __syncthreads();
    if (t == 0) {
        double a0=0, a1=0, a2=0, a3=0; uint_t a4=0;
#pragma unroll
        for (int w = 0; w < 16; ++w) { a0+=s0[w]; a1+=s1[w]; a2+=s2[w]; a3+=s3[w]; a4+=s4[w]; }
        out[0] = (float)(a2 > 0.0 ? a0 / a2 : 0.0);
        out[1] = (float)((double)a4 / (double)NROWS);
        out[2] = (float)(a3 / ((double)NROWS * 3.0));
        out[3] = (float)(a1 / ((double)NROWS * (double)(NROWS - KCLS)));
    }
}

extern "C" void kernel_launch(void* const* d_in, const int* in_sizes, int n_in,
                              void* d_out, int out_size, void* d_ws, size_t ws_size,
                              hipStream_t stream)
{
    const float* x = (const float*)d_in[0];
    float* out = (float*)d_out;
    char* ws = (char*)d_ws;

    uint_t*   imask    = (uint_t*)(ws + 0);          // 512
    uint_t*   jmask    = (uint_t*)(ws + 512);        // 512
    float*    sqn      = (float*)(ws + 1024);        // 16K
    float*    posd     = (float*)(ws + 17408);       // 64K (4096 x float4)
    float4*   partial  = (float4*)(ws + 82944);      // 33280
    ushort_t* xf       = (ushort_t*)(ws + 116224);   // 2 MB fragment-major
    uint_t*   imask2   = (uint_t*)(ws + 2213376);    // 512 (ablation)
    uint_t*   jmask2   = (uint_t*)(ws + 2213888);    // 512
    float4*   partial2 = (float4*)(ws + 2214400);    // 33280
    float*    sB       = (float*)(ws + 2247680);     // 33280
    float*    sD       = (float*)(ws + 2280960);     // 8320

    k_prep<<<1024, 256, 0, stream>>>(x, sqn, posd, xf, imask, jmask);
    k_tiles<<<NTRI, 256, 0, stream>>>(xf, sqn, (const float4*)posd,
                                      imask, jmask, partial);
    k_final<<<1, 1024, 0, stream>>>(imask, jmask, partial,
                                    (const float4*)posd, out);

    // diagnostic ablations (outputs unused; per-dispatch rocprof rows)
    kt_ldm<<<NTRI, 256, 0, stream>>>(xf, sB);
    kt_epi<<<NTRI, 256, 0, stream>>>(sqn, (const float4*)posd,
                                     imask2, jmask2, partial2);
    kt_shell<<<NTRI, 256, 0, stream>>>(sD);
}

// Round 9
// 165.500 us; speedup vs baseline: 1.5621x; 1.5621x over previous
//
#include <hip/hip_runtime.h>

#define NROWS 4096
#define DIM   128
#define KCLS  4
#define NTILE 64                 // 64x64 anchor tiles
#define NTRI  2080               // NTILE*(NTILE+1)/2 triangular tiles
#define GRID2 2048               // k_tiles grid (grid-stride the extra 32)
#define MARGIN_F 0.02f
#define EPS_F    1e-12f

typedef unsigned short ushort_t;
typedef unsigned int   uint_t;
typedef __attribute__((ext_vector_type(8)))  short bf16x8;
typedef __attribute__((ext_vector_type(16))) float f32x16;

__device__ __forceinline__ ushort_t rne_bf16(float v, float& back) {
    uint_t u = __float_as_uint(v);
    uint_t r = (u + 0x7fffu + ((u >> 16) & 1u)) >> 16;
    back = __uint_as_float(r << 16);
    return (ushort_t)r;
}

__device__ __forceinline__ bf16x8 pack8(const ushort_t* h) {
    bf16x8 v;
#pragma unroll
    for (int e = 0; e < 8; ++e) v[e] = (short)h[e];
    return v;
}

// fast HW sqrt (~1 ulp; distances O(10), margin 0.02 -> plenty)
__device__ __forceinline__ float fsqrt(float x) {
    float r;
    asm("v_sqrt_f32 %0, %1" : "=v"(r) : "v"(x));
    return r;
}

// triangular decode: bid -> (ti, tj), tj >= ti
__device__ __forceinline__ void tri_decode(int bid, int& ti, int& tj) {
    const int bidp = (NTRI - 1) - bid;
    int m = (int)((sqrtf((float)(8 * bidp + 1)) - 1.0f) * 0.5f);
    while ((m + 1) * (m + 2) / 2 <= bidp) ++m;
    while (m * (m + 1) / 2 > bidp) --m;
    ti = (NTILE - 1) - m;
    tj = (NTILE - 1) - (bidp - m * (m + 1) / 2);
}

// ---------------- kernel 1: wave-per-class prep ----------------
// One 64-lane wave handles one class (4 rows): norms, the 6 intra-class
// distances (XOR pairing), spd={sq,p0,p1,p2}, bf16 hi/lo fragment-major xf.
__global__ __launch_bounds__(256) void k_prep(
    const float* __restrict__ x,
    float4* __restrict__ spd,
    ushort_t* __restrict__ xf,
    uint_t* __restrict__ imask, uint_t* __restrict__ jmask)
{
    if (blockIdx.x == 0) {
        const int tt = threadIdx.x;
        if (tt < 128) imask[tt] = 0u; else jmask[tt - 128] = 0u;
    }
    const int wave = threadIdx.x >> 6, lane = threadIdx.x & 63;
    const int cls  = (blockIdx.x << 2) + wave;      // 0..1023
    const int r0   = lane >> 4;                     // row in class
    const int cseg = lane & 15;                     // 8-col segment
    const int row  = (cls << 2) + r0;

    const float4* rp = (const float4*)(x + (size_t)row * DIM + (cseg << 3));
    const float4 v0 = rp[0], v1 = rp[1];
    float vs[8] = {v0.x, v0.y, v0.z, v0.w, v1.x, v1.y, v1.z, v1.w};

    // per-row squared norm
    float sq = 0.f;
#pragma unroll
    for (int e = 0; e < 8; ++e) sq = fmaf(vs[e], vs[e], sq);
#pragma unroll
    for (int off = 1; off < 16; off <<= 1) sq += __shfl_xor(sq, off, 16);

    float sq4[4];
#pragma unroll
    for (int s = 0; s < 4; ++s) sq4[s] = __shfl(sq, (s << 4) | cseg);

    // 3 pair distances per row via XOR matching (delta=1,2,3)
    float dl[3];
#pragma unroll
    for (int delta = 1; delta <= 3; ++delta) {
        const int p = r0 ^ delta;
        float dot = 0.f;
#pragma unroll
        for (int e = 0; e < 8; ++e) {
            const float o = __shfl(vs[e], (p << 4) | cseg);
            dot = fmaf(vs[e], o, dot);
        }
#pragma unroll
        for (int off = 1; off < 16; off <<= 1) dot += __shfl_xor(dot, off, 16);
        dl[delta - 1] = fsqrt(fmaxf(sq4[r0] + sq4[p] - 2.f * dot, EPS_F));
    }
    // order positives by ascending partner index (reference's o-order)
    float po[3];
#pragma unroll
    for (int o = 0; o < 3; ++o) {
        const int s = o + (o >= r0 ? 1 : 0);
        const int d = r0 ^ s;
        po[o] = (d == 1) ? dl[0] : (d == 2) ? dl[1] : dl[2];
    }
    if (cseg == 0) spd[row] = make_float4(sq4[r0], po[0], po[1], po[2]);

    // bf16 hi/lo split, fragment-major xf (same layout as validated round 8)
    ushort_t hs[8], ls[8];
#pragma unroll
    for (int e = 0; e < 8; ++e) {
        float back, d_;
        hs[e] = rne_bf16(vs[e], back);
        ls[e] = rne_bf16(vs[e] - back, d_);
    }
    const int band = row >> 5, L = row & 31, cb = cseg >> 1, sf = cseg & 1;
    ushort_t* dst = xf + ((size_t)((band << 3) + cb) << 1) * 512
                       + (((sf << 5) + L) << 3);
    *(bf16x8*)dst         = pack8(hs);
    *(bf16x8*)(dst + 512) = pack8(ls);
}

// ---------------- kernel 2: MFMA Gram + fused hinge ----------------
__global__ __launch_bounds__(256, 4) void k_tiles(
    const ushort_t* __restrict__ xf,
    const float4* __restrict__ spd,
    uint_t* __restrict__ imask, uint_t* __restrict__ jmask,
    float4* __restrict__ partial)
{
    const int t    = threadIdx.x;
    const int wave = t >> 6, lane = t & 63;
    const int wr = wave >> 1, wc = wave & 1;
    const int col = lane & 31, hi = lane >> 5;

    __shared__ float4 wpart[4];

    for (int bid = blockIdx.x; bid < NTRI; bid += GRID2) {
        int ti, tj;
        tri_decode(bid, ti, tj);
        const int ibase = ti << 6, jbase = tj << 6;
        const bool diag = (ti == tj);

        const int bi = (ti << 1) + wr, bj = (tj << 1) + wc;
        const ushort_t* pa = xf + (size_t)bi * 8192 + lane * 8;
        const ushort_t* pb = xf + (size_t)bj * 8192 + lane * 8;

        f32x16 acc;
#pragma unroll
        for (int r = 0; r < 16; ++r) acc[r] = 0.f;

#pragma unroll
        for (int c = 0; c < 8; ++c) {
            const bf16x8 ah = *(const bf16x8*)(pa + c * 1024);
            const bf16x8 al = *(const bf16x8*)(pa + c * 1024 + 512);
            const bf16x8 bh = *(const bf16x8*)(pb + c * 1024);
            const bf16x8 bl = *(const bf16x8*)(pb + c * 1024 + 512);
            acc = __builtin_amdgcn_mfma_f32_32x32x16_bf16(ah, bh, acc, 0, 0, 0);
            acc = __builtin_amdgcn_mfma_f32_32x32x16_bf16(ah, bl, acc, 0, 0, 0);
            acc = __builtin_amdgcn_mfma_f32_32x32x16_bf16(al, bh, acc, 0, 0, 0);
        }

        // ---------------- epilogue: no shuffles, broadcast loads ------------
        const int jg = jbase + (wc << 5) + col;
        const float4 sj = spd[jg];                  // per-lane gather (hoisted)
        const int jcls = jg >> 2;

        float ts = 0.f, ns = 0.f, cntf = 0.f;
        uint_t iam = 0, jany = 0;
#pragma unroll
        for (int r = 0; r < 16; ++r) {
            const int rbase = (r & 3) + ((r >> 2) << 3);    // C/D row map
            const int src = rbase + (hi << 2);
            const int i = ibase + (wr << 5) + src;
            const float4 si = spd[i];               // uniform per half-wave
            const bool skip = diag && ((i >> 2) == jcls);
            const float dd =
                fsqrt(fmaxf(si.x + sj.x - 2.f * acc[r], EPS_F));
            if (!skip) {
                ns += dd;                                   // anchor i
                const float t0 = si.y + MARGIN_F - dd;
                const float t1 = si.z + MARGIN_F - dd;
                const float t2 = si.w + MARGIN_F - dd;
                uint_t v = 0;
                if (t0 > 0.f) { ts += t0; cntf += 1.f; v = 1u; }
                if (t1 > 0.f) { ts += t1; cntf += 1.f; v = 1u; }
                if (t2 > 0.f) { ts += t2; cntf += 1.f; v = 1u; }
                iam |= v << r;
                if (!diag) {                                // anchor j
                    ns += dd;
                    const float u0 = sj.y + MARGIN_F - dd;
                    const float u1 = sj.z + MARGIN_F - dd;
                    const float u2 = sj.w + MARGIN_F - dd;
                    if (u0 > 0.f) { ts += u0; cntf += 1.f; jany = 1u; }
                    if (u1 > 0.f) { ts += u1; cntf += 1.f; jany = 1u; }
                    if (u2 > 0.f) { ts += u2; cntf += 1.f; jany = 1u; }
                }
            }
        }

        // i-flags: OR-reduce per 32-lane half, remap reg-bits -> row-bits
        uint_t iam_all = iam;
#pragma unroll
        for (int off = 1; off < 32; off <<= 1)
            iam_all |= __shfl_xor(iam_all, off);
        uint_t rowmask = 0;
#pragma unroll
        for (int r = 0; r < 16; ++r)
            if ((iam_all >> r) & 1u)
                rowmask |= 1u << ((r & 3) + ((r >> 2) << 3) + (hi << 2));
        if ((lane == 0 || lane == 32) && rowmask)
            atomicOr(&imask[(ti << 1) + wr], rowmask);

        const unsigned long long bm = __ballot(jany != 0);
        const uint_t jm = (uint_t)bm | (uint_t)(bm >> 32);
        if (lane == 0 && jm) atomicOr(&jmask[(tj << 1) + wc], jm);

        // scalar partials
#pragma unroll
        for (int off = 32; off; off >>= 1) {
            ts   += __shfl_down(ts, off);
            ns   += __shfl_down(ns, off);
            cntf += __shfl_down(cntf, off);
        }
        if (lane == 0) wpart[wave] = make_float4(ts, ns, cntf, 0.f);
        __syncthreads();
        if (t == 0) {
            float4 s = wpart[0];
            s.x += wpart[1].x + wpart[2].x + wpart[3].x;
            s.y += wpart[1].y + wpart[2].y + wpart[3].y;
            s.z += wpart[1].z + wpart[2].z + wpart[3].z;
            partial[bid] = s;
        }
        __syncthreads();   // protect wpart before next grid-stride iter
    }
}

// ---------------- kernel 3: finalize ----------------
__global__ void k_final(const uint_t* __restrict__ imask,
                        const uint_t* __restrict__ jmask,
                        const float4* __restrict__ partial,
                        const float4* __restrict__ spd,
                        float* __restrict__ out)
{
    const int t = threadIdx.x;      // 1024
    const int lane = t & 63, wave = t >> 6;
    double ts = 0.0, ns = 0.0, cnt = 0.0, ps = 0.0;
    uint_t zc = 0;

    for (int idx = t; idx < NTRI; idx += 1024) {
        const float4 p = partial[idx];
        ts += (double)p.x; ns += (double)p.y; cnt += (double)p.z;
    }
    for (int idx = t; idx < NROWS; idx += 1024) {
        const float4 p = spd[idx];
        ps += (double)p.y + (double)p.z + (double)p.w;
    }
    if (t < 128) zc = 32u - (uint_t)__popc(imask[t] | jmask[t]);

#pragma unroll
    for (int off = 32; off; off >>= 1) {
        ts  += __shfl_down(ts, off);
        ns  += __shfl_down(ns, off);
        cnt += __shfl_down(cnt, off);
        ps  += __shfl_down(ps, off);
        zc  += __shfl_down(zc, off);
    }
    __shared__ double s0[16], s1[16], s2[16], s3[16];
    __shared__ uint_t s4[16];
    if (lane == 0) { s0[wave]=ts; s1[wave]=ns; s2[wave]=cnt; s3[wave]=ps; s4[wave]=zc; }
    __syncthreads();
    if (t == 0) {
        double a0=0, a1=0, a2=0, a3=0; uint_t a4=0;
#pragma unroll
        for (int w = 0; w < 16; ++w) { a0+=s0[w]; a1+=s1[w]; a2+=s2[w]; a3+=s3[w]; a4+=s4[w]; }
        out[0] = (float)(a2 > 0.0 ? a0 / a2 : 0.0);
        out[1] = (float)((double)a4 / (double)NROWS);
        out[2] = (float)(a3 / ((double)NROWS * 3.0));
        out[3] = (float)(a1 / ((double)NROWS * (double)(NROWS - KCLS)));
    }
}

extern "C" void kernel_launch(void* const* d_in, const int* in_sizes, int n_in,
                              void* d_out, int out_size, void* d_ws, size_t ws_size,
                              hipStream_t stream)
{
    const float* x = (const float*)d_in[0];
    float* out = (float*)d_out;
    char* ws = (char*)d_ws;

    // imask 512 | jmask 512 | spd 64K | partial 33280 | xf 2MB
    uint_t*   imask   = (uint_t*)(ws + 0);
    uint_t*   jmask   = (uint_t*)(ws + 512);
    float4*   spd     = (float4*)(ws + 1024);
    float4*   partial = (float4*)(ws + 1024 + 65536);
    ushort_t* xf      = (ushort_t*)(ws + 1024 + 65536 + 33280);

    k_prep<<<256, 256, 0, stream>>>(x, spd, xf, imask, jmask);
    k_tiles<<<GRID2, 256, 0, stream>>>(xf, spd, imask, jmask, partial);
    k_final<<<1, 1024, 0, stream>>>(imask, jmask, partial, spd, out);
}

// Round 10
// 110.955 us; speedup vs baseline: 2.3300x; 1.4916x over previous
//
#include <hip/hip_runtime.h>

#define NROWS 4096
#define DIM   128
#define KCLS  4
#define NBLK  1056               // sum_{tJ=0..31} (2*tJ+2)
#define MARGIN_F 0.02f
#define EPS_F    1e-12f

typedef unsigned short ushort_t;
typedef unsigned int   uint_t;
typedef __attribute__((ext_vector_type(8)))  short bf16x8;
typedef __attribute__((ext_vector_type(16))) float f32x16;

__device__ __forceinline__ ushort_t rne_bf16(float v, float& back) {
    uint_t u = __float_as_uint(v);
    uint_t r = (u + 0x7fffu + ((u >> 16) & 1u)) >> 16;
    back = __uint_as_float(r << 16);
    return (ushort_t)r;
}

__device__ __forceinline__ bf16x8 pack8(const ushort_t* h) {
    bf16x8 v;
#pragma unroll
    for (int e = 0; e < 8; ++e) v[e] = (short)h[e];
    return v;
}

__device__ __forceinline__ float fsqrt(float x) {
    float r;
    asm("v_sqrt_f32 %0, %1" : "=v"(r) : "v"(x));
    return r;
}

// blocks ordered tJ ascending, ti in 0..2tJ+1; start(tJ)=tJ*(tJ+1)
__device__ __forceinline__ void blk_decode(int bid, int& ti, int& tJ) {
    tJ = (int)((sqrtf((float)(4 * bid + 1)) - 1.0f) * 0.5f);
    while ((tJ + 1) * (tJ + 2) <= bid) ++tJ;
    while (tJ * (tJ + 1) > bid) --tJ;
    ti = bid - tJ * (tJ + 1);
}

// ---------------- kernel 1: wave-per-class prep (validated R9) ----------
__global__ __launch_bounds__(256) void k_prep(
    const float* __restrict__ x,
    float4* __restrict__ spd,
    ushort_t* __restrict__ xf,
    uint_t* __restrict__ imask, uint_t* __restrict__ jmask)
{
    if (blockIdx.x == 0) {
        const int tt = threadIdx.x;
        if (tt < 128) imask[tt] = 0u; else jmask[tt - 128] = 0u;
    }
    const int wave = threadIdx.x >> 6, lane = threadIdx.x & 63;
    const int cls  = (blockIdx.x << 2) + wave;
    const int r0   = lane >> 4;
    const int cseg = lane & 15;
    const int row  = (cls << 2) + r0;

    const float4* rp = (const float4*)(x + (size_t)row * DIM + (cseg << 3));
    const float4 v0 = rp[0], v1 = rp[1];
    float vs[8] = {v0.x, v0.y, v0.z, v0.w, v1.x, v1.y, v1.z, v1.w};

    float sq = 0.f;
#pragma unroll
    for (int e = 0; e < 8; ++e) sq = fmaf(vs[e], vs[e], sq);
#pragma unroll
    for (int off = 1; off < 16; off <<= 1) sq += __shfl_xor(sq, off, 16);

    float sq4[4];
#pragma unroll
    for (int s = 0; s < 4; ++s) sq4[s] = __shfl(sq, (s << 4) | cseg);

    float dl[3];
#pragma unroll
    for (int delta = 1; delta <= 3; ++delta) {
        const int p = r0 ^ delta;
        float dot = 0.f;
#pragma unroll
        for (int e = 0; e < 8; ++e) {
            const float o = __shfl(vs[e], (p << 4) | cseg);
            dot = fmaf(vs[e], o, dot);
        }
#pragma unroll
        for (int off = 1; off < 16; off <<= 1) dot += __shfl_xor(dot, off, 16);
        dl[delta - 1] = fsqrt(fmaxf(sq4[r0] + sq4[p] - 2.f * dot, EPS_F));
    }
    float po[3];
#pragma unroll
    for (int o = 0; o < 3; ++o) {
        const int s = o + (o >= r0 ? 1 : 0);
        const int d = r0 ^ s;
        po[o] = (d == 1) ? dl[0] : (d == 2) ? dl[1] : dl[2];
    }
    if (cseg == 0) spd[row] = make_float4(sq4[r0], po[0], po[1], po[2]);

    ushort_t hs[8], ls[8];
#pragma unroll
    for (int e = 0; e < 8; ++e) {
        float back, d_;
        hs[e] = rne_bf16(vs[e], back);
        ls[e] = rne_bf16(vs[e] - back, d_);
    }
    const int band = row >> 5, L = row & 31, cb = cseg >> 1, sf = cseg & 1;
    ushort_t* dst = xf + ((size_t)((band << 3) + cb) << 1) * 512
                       + (((sf << 5) + L) << 3);
    *(bf16x8*)dst         = pack8(hs);
    *(bf16x8*)(dst + 512) = pack8(ls);
}

// ---------------- kernel 2: MFMA Gram + fused hinge -------------------
// Block = 64 rows x 128 cols; wave (wr,wc) = 32 rows x 64 cols (2 bands,
// both in 64-tile tj64 = 2tJ+wc). No global loads in the epilogue: row-spd
// via LDS (T14 staged), col-spd hoisted to regs before the MFMA loop.
__global__ __launch_bounds__(256, 4) void k_tiles(
    const ushort_t* __restrict__ xf,
    const float4* __restrict__ spd,
    uint_t* __restrict__ imask, uint_t* __restrict__ jmask,
    float4* __restrict__ partial)
{
    int ti, tJ;
    blk_decode((int)blockIdx.x, ti, tJ);

    const int t = threadIdx.x, wave = t >> 6, lane = t & 63;
    const int wr = wave >> 1, wc = wave & 1;
    const int col = lane & 31, hi = lane >> 5;
    const int ibase = ti << 6;
    const int tj64 = (tJ << 1) + wc;
    const bool active   = (tj64 >= ti);
    const bool anchor_j = (tj64 > ti);
    const int jb  = (tJ << 2) + (wc << 1);     // first 32-band index
    const int jg0 = (jb << 5) + col;
    const int jg1 = jg0 + 32;

    __shared__ float4 spd_i[64];
    __shared__ float4 wpart[4];

    // T14: issue row-spd load now, consume after the MFMA phase
    float4 myspd;
    if (t < 64) myspd = spd[ibase + t];
    // hoist j-side spd (2 vector loads, latency hides under MFMA)
    const float4 sj0 = spd[jg0];
    const float4 sj1 = spd[jg1];

    const ushort_t* pa  = xf + (size_t)((ti << 1) + wr) * 8192 + lane * 8;
    const ushort_t* pb0 = xf + (size_t)jb * 8192 + lane * 8;
    const ushort_t* pb1 = pb0 + 8192;

    f32x16 acc0, acc1;
#pragma unroll
    for (int r = 0; r < 16; ++r) { acc0[r] = 0.f; acc1[r] = 0.f; }

#pragma unroll
    for (int c = 0; c < 8; ++c) {
        const bf16x8 ah  = *(const bf16x8*)(pa  + c * 1024);
        const bf16x8 al  = *(const bf16x8*)(pa  + c * 1024 + 512);
        const bf16x8 b0h = *(const bf16x8*)(pb0 + c * 1024);
        const bf16x8 b0l = *(const bf16x8*)(pb0 + c * 1024 + 512);
        const bf16x8 b1h = *(const bf16x8*)(pb1 + c * 1024);
        const bf16x8 b1l = *(const bf16x8*)(pb1 + c * 1024 + 512);
        acc0 = __builtin_amdgcn_mfma_f32_32x32x16_bf16(ah, b0h, acc0, 0, 0, 0);
        acc1 = __builtin_amdgcn_mfma_f32_32x32x16_bf16(ah, b1h, acc1, 0, 0, 0);
        acc0 = __builtin_amdgcn_mfma_f32_32x32x16_bf16(ah, b0l, acc0, 0, 0, 0);
        acc1 = __builtin_amdgcn_mfma_f32_32x32x16_bf16(ah, b1l, acc1, 0, 0, 0);
        acc0 = __builtin_amdgcn_mfma_f32_32x32x16_bf16(al, b0h, acc0, 0, 0, 0);
        acc1 = __builtin_amdgcn_mfma_f32_32x32x16_bf16(al, b1h, acc1, 0, 0, 0);
    }

    if (t < 64) spd_i[t] = myspd;      // vmcnt waits here, after MFMA
    __syncthreads();

    float ts = 0.f, ns = 0.f, cntf = 0.f;
    uint_t iam = 0, jany0 = 0, jany1 = 0;

    if (active) {
        const int jcls0 = jg0 >> 2, jcls1 = jg1 >> 2;
        const float nsw = anchor_j ? 2.f : 1.f;
#pragma unroll
        for (int r = 0; r < 16; ++r) {
            const int src = (r & 3) + ((r >> 2) << 3) + (hi << 2);
            const float4 si = spd_i[(wr << 5) + src];       // LDS broadcast
            const int icls = (ibase + (wr << 5) + src) >> 2;

            // ---- band 0 ----
            {
                const float dd = fsqrt(fmaxf(si.x + sj0.x - 2.f * acc0[r], EPS_F));
                const bool skip = !anchor_j && (icls == jcls0);
                if (!skip) {
                    ns += nsw * dd;
                    uint_t v = 0; float h;
                    h = si.y + MARGIN_F - dd; if (h > 0.f) { ts += h; cntf += 1.f; v = 1u; }
                    h = si.z + MARGIN_F - dd; if (h > 0.f) { ts += h; cntf += 1.f; v = 1u; }
                    h = si.w + MARGIN_F - dd; if (h > 0.f) { ts += h; cntf += 1.f; v = 1u; }
                    iam |= v << r;
                    if (anchor_j) {
                        h = sj0.y + MARGIN_F - dd; if (h > 0.f) { ts += h; cntf += 1.f; jany0 = 1u; }
                        h = sj0.z + MARGIN_F - dd; if (h > 0.f) { ts += h; cntf += 1.f; jany0 = 1u; }
                        h = sj0.w + MARGIN_F - dd; if (h > 0.f) { ts += h; cntf += 1.f; jany0 = 1u; }
                    }
                }
            }
            // ---- band 1 ----
            {
                const float dd = fsqrt(fmaxf(si.x + sj1.x - 2.f * acc1[r], EPS_F));
                const bool skip = !anchor_j && (icls == jcls1);
                if (!skip) {
                    ns += nsw * dd;
                    uint_t v = 0; float h;
                    h = si.y + MARGIN_F - dd; if (h > 0.f) { ts += h; cntf += 1.f; v = 1u; }
                    h = si.z + MARGIN_F - dd; if (h > 0.f) { ts += h; cntf += 1.f; v = 1u; }
                    h = si.w + MARGIN_F - dd; if (h > 0.f) { ts += h; cntf += 1.f; v = 1u; }
                    iam |= v << r;
                    if (anchor_j) {
                        h = sj1.y + MARGIN_F - dd; if (h > 0.f) { ts += h; cntf += 1.f; jany1 = 1u; }
                        h = sj1.z + MARGIN_F - dd; if (h > 0.f) { ts += h; cntf += 1.f; jany1 = 1u; }
                        h = sj1.w + MARGIN_F - dd; if (h > 0.f) { ts += h; cntf += 1.f; jany1 = 1u; }
                    }
                }
            }
        }

        // i-flags: OR across wave halves, remap reg bits -> row bits
        uint_t iam_all = iam;
#pragma unroll
        for (int off = 1; off < 32; off <<= 1)
            iam_all |= __shfl_xor(iam_all, off);
        uint_t rowmask = 0;
#pragma unroll
        for (int r = 0; r < 16; ++r)
            if ((iam_all >> r) & 1u)
                rowmask |= 1u << ((r & 3) + ((r >> 2) << 3) + (hi << 2));
        if ((lane == 0 || lane == 32) && rowmask)
            atomicOr(&imask[(ti << 1) + wr], rowmask);

        if (anchor_j) {
            const unsigned long long b0 = __ballot(jany0 != 0);
            const uint_t m0 = (uint_t)b0 | (uint_t)(b0 >> 32);
            if (lane == 0 && m0) atomicOr(&jmask[jb], m0);
            const unsigned long long b1 = __ballot(jany1 != 0);
            const uint_t m1 = (uint_t)b1 | (uint_t)(b1 >> 32);
            if (lane == 0 && m1) atomicOr(&jmask[jb + 1], m1);
        }
    }

    // block scalar partials (zeros for inactive waves)
#pragma unroll
    for (int off = 32; off; off >>= 1) {
        ts   += __shfl_down(ts, off);
        ns   += __shfl_down(ns, off);
        cntf += __shfl_down(cntf, off);
    }
    if (lane == 0) wpart[wave] = make_float4(ts, ns, cntf, 0.f);
    __syncthreads();
    if (t == 0) {
        float4 s = wpart[0];
        s.x += wpart[1].x + wpart[2].x + wpart[3].x;
        s.y += wpart[1].y + wpart[2].y + wpart[3].y;
        s.z += wpart[1].z + wpart[2].z + wpart[3].z;
        partial[blockIdx.x] = s;
    }
}

// ---------------- kernel 3: finalize ----------------
__global__ void k_final(const uint_t* __restrict__ imask,
                        const uint_t* __restrict__ jmask,
                        const float4* __restrict__ partial,
                        const float4* __restrict__ spd,
                        float* __restrict__ out)
{
    const int t = threadIdx.x;      // 1024
    const int lane = t & 63, wave = t >> 6;
    double ts = 0.0, ns = 0.0, cnt = 0.0, ps = 0.0;
    uint_t zc = 0;

    for (int idx = t; idx < NBLK; idx += 1024) {
        const float4 p = partial[idx];
        ts += (double)p.x; ns += (double)p.y; cnt += (double)p.z;
    }
    for (int idx = t; idx < NROWS; idx += 1024) {
        const float4 p = spd[idx];
        ps += (double)p.y + (double)p.z + (double)p.w;
    }
    if (t < 128) zc = 32u - (uint_t)__popc(imask[t] | jmask[t]);

#pragma unroll
    for (int off = 32; off; off >>= 1) {
        ts  += __shfl_down(ts, off);
        ns  += __shfl_down(ns, off);
        cnt += __shfl_down(cnt, off);
        ps  += __shfl_down(ps, off);
        zc  += __shfl_down(zc, off);
    }
    __shared__ double s0[16], s1[16], s2[16], s3[16];
    __shared__ uint_t s4[16];
    if (lane == 0) { s0[wave]=ts; s1[wave]=ns; s2[wave]=cnt; s3[wave]=ps; s4[wave]=zc; }
    __syncthreads();
    if (t == 0) {
        double a0=0, a1=0, a2=0, a3=0; uint_t a4=0;
#pragma unroll
        for (int w = 0; w < 16; ++w) { a0+=s0[w]; a1+=s1[w]; a2+=s2[w]; a3+=s3[w]; a4+=s4[w]; }
        out[0] = (float)(a2 > 0.0 ? a0 / a2 : 0.0);
        out[1] = (float)((double)a4 / (double)NROWS);
        out[2] = (float)(a3 / ((double)NROWS * 3.0));
        out[3] = (float)(a1 / ((double)NROWS * (double)(NROWS - KCLS)));
    }
}

extern "C" void kernel_launch(void* const* d_in, const int* in_sizes, int n_in,
                              void* d_out, int out_size, void* d_ws, size_t ws_size,
                              hipStream_t stream)
{
    const float* x = (const float*)d_in[0];
    float* out = (float*)d_out;
    char* ws = (char*)d_ws;

    // imask 512 | jmask 512 | spd 64K | partial NBLK*16 | xf 2MB
    uint_t*   imask   = (uint_t*)(ws + 0);
    uint_t*   jmask   = (uint_t*)(ws + 512);
    float4*   spd     = (float4*)(ws + 1024);
    float4*   partial = (float4*)(ws + 1024 + 65536);
    ushort_t* xf      = (ushort_t*)(ws + 1024 + 65536 + 16896);

    k_prep<<<256, 256, 0, stream>>>(x, spd, xf, imask, jmask);
    k_tiles<<<NBLK, 256, 0, stream>>>(xf, spd, imask, jmask, partial);
    k_final<<<1, 1024, 0, stream>>>(imask, jmask, partial, spd, out);
}